// Round 6
// baseline (560.070 us; speedup 1.0000x reference)
//
#include <hip/hip_runtime.h>

// Problem geometry (compile-time constants from the reference).
static constexpr int XD = 400;
static constexpr int YD = 400;
static constexpr int ZD = 8;
static constexpr int CD = 64;                          // channels per cell
static constexpr int NCELLS = XD * YD * ZD;            // 1,280,000 cells
static constexpr long long CELL_F4  = CD / 4;          // 16 float4 per cell row
static constexpr long long TOTAL_F4 = (long long)NCELLS * CELL_F4;  // 20.48M

// Native clang vector type — required by __builtin_nontemporal_load/store.
typedef float vfloat4 __attribute__((ext_vector_type(4)));

// 1) winner[cell] = -1 (explicit init; ~5 MB, ~2 us).
__global__ void init_winner_kernel(int* __restrict__ w, int n) {
    int i = blockIdx.x * blockDim.x + threadIdx.x;
    if (i < n) w[i] = -1;
}

// 2) last-write-wins: highest update index claims the cell.
//    (XLA .at[].set applies updates in order; last duplicate wins.)
__global__ void winner_kernel(const int* __restrict__ idx,
                              int* __restrict__ w, int n) {
    int i = blockIdx.x * blockDim.x + threadIdx.x;
    if (i >= n) return;
    int ix = idx[3 * i + 0];
    int iy = idx[3 * i + 1];
    int iz = idx[3 * i + 2];
    int cell = (ix * YD + iy) * ZD + iz;
    atomicMax(&w[cell], i);
}

// 3) plain streaming copy voxel -> out. No branches, no dependent loads —
//    the exact pattern measured at 6.29 TB/s (m13). Nontemporal both ways
//    (read-once / write-once; the scatter rewrite touches only ~10% later).
__global__ void __launch_bounds__(256)
copy_kernel(const vfloat4* __restrict__ src, vfloat4* __restrict__ dst) {
    long long stride = (long long)gridDim.x * blockDim.x;
    for (long long i = (long long)blockIdx.x * blockDim.x + threadIdx.x;
         i < TOTAL_F4; i += stride) {
        __builtin_nontemporal_store(__builtin_nontemporal_load(&src[i]), &dst[i]);
    }
}

// 4) winning rows overwrite their cell (16 threads x float4 = contiguous 256B).
__global__ void scatter_kernel(const int* __restrict__ idx,
                               const vfloat4* __restrict__ pixels,
                               const int* __restrict__ w,
                               vfloat4* __restrict__ out, int n) {
    int t = blockIdx.x * blockDim.x + threadIdx.x;
    int i = t >> 4;          // update row
    int c = t & 15;          // float4 slot within the 64-float row
    if (i >= n) return;
    int ix = idx[3 * i + 0];
    int iy = idx[3 * i + 1];
    int iz = idx[3 * i + 2];
    int cell = (ix * YD + iy) * ZD + iz;
    if (w[cell] != i) return;            // a later duplicate owns this cell
    out[(long long)cell * CELL_F4 + c] = pixels[(long long)i * CELL_F4 + c];
}

extern "C" void kernel_launch(void* const* d_in, const int* in_sizes, int n_in,
                              void* d_out, int out_size, void* d_ws, size_t ws_size,
                              hipStream_t stream) {
    const vfloat4* voxel  = (const vfloat4*)d_in[0];
    const int*     sidx   = (const int*)d_in[1];
    const vfloat4* pixels = (const vfloat4*)d_in[2];
    vfloat4*       out4   = (vfloat4*)d_out;
    int*           winner = (int*)d_ws;                // 1.28M ints = 5.12 MB

    const int N = in_sizes[1] / 3;                     // 134,400 updates

    // 1) init winner array
    {
        int threads = 256;
        int blocks = (NCELLS + threads - 1) / threads;
        init_winner_kernel<<<blocks, threads, 0, stream>>>(winner, NCELLS);
    }
    // 2) resolve duplicate cells (last index wins)
    {
        int threads = 256;
        int blocks = (N + threads - 1) / threads;
        winner_kernel<<<blocks, threads, 0, stream>>>(sidx, winner, N);
    }
    // 3) bulk copy voxel -> out (pure stream, proven 6.3 TB/s pattern)
    {
        int threads = 256;
        int blocks  = 4096;
        copy_kernel<<<blocks, threads, 0, stream>>>(voxel, out4);
    }
    // 4) scatter winning rows (~34 MB, ~15 us)
    {
        int threads = 256;
        long long total = (long long)N * 16;
        int blocks = (int)((total + threads - 1) / threads);
        scatter_kernel<<<blocks, threads, 0, stream>>>(sidx, pixels, winner, out4, N);
    }
}